// Round 1
// 213.878 us; speedup vs baseline: 1.1650x; 1.1650x over previous
//
#include <hip/hip_runtime.h>
#include <hip/hip_fp16.h>

#define N_NODES 50000
#define N_EDGES 800000
#define D 64
#define NLAYER 5
#define NUM_GRAPHS 512
#define NOUT 768

#define SUPW 512                 // dst nodes per super-bucket
#define NSUPER 98                // ceil(50000/512)
#define PART_EDGES 4096          // edges per partition block
#define PART_BLOCKS 196          // ceil(800000/4096)
#define CSR_CAP 16384            // LDS staging cap per super (avg ~8163)

// ---------------- CSR build v3: LDS-staged two-level counting sort ----------------

__global__ __launch_bounds__(128) void zero_super_kernel(int* __restrict__ superCnt) {
    int i = threadIdx.x;
    if (i < NSUPER) superCnt[i] = 0;
}

__global__ __launch_bounds__(256) void hist_super_kernel(const int* __restrict__ dst,
                                                         int* __restrict__ superCnt) {
    __shared__ int h[NSUPER];
    int t = threadIdx.x;
    if (t < NSUPER) h[t] = 0;
    __syncthreads();
    int e0 = blockIdx.x * PART_EDGES;
    int eN = min(e0 + PART_EDGES, N_EDGES) - e0;
    for (int i = t; i < eN; i += 256) atomicAdd(&h[dst[e0 + i] >> 9], 1);
    __syncthreads();
    if (t < NSUPER) atomicAdd(&superCnt[t], h[t]);
}

__global__ __launch_bounds__(128) void scan_super_kernel(const int* __restrict__ superCnt,
                                                         int* __restrict__ superBase,
                                                         int* __restrict__ superCur) {
    if (threadIdx.x == 0) {
        int run = 0;
        for (int s = 0; s < NSUPER; ++s) {
            superBase[s] = run; superCur[s] = run; run += superCnt[s];
        }
        superBase[NSUPER] = run;  // == N_EDGES
    }
}

__global__ __launch_bounds__(1024) void partition_kernel(
    const int* __restrict__ src, const int* __restrict__ dst,
    int* __restrict__ superCur, unsigned* __restrict__ ebuf) {
    __shared__ int hist[NSUPER];
    __shared__ int pref[NSUPER + 1];
    __shared__ int base[NSUPER];
    __shared__ int curs[NSUPER];
    __shared__ unsigned out[PART_EDGES];
    int t = threadIdx.x;
    int e0 = blockIdx.x * PART_EDGES;
    int eN = min(e0 + PART_EDGES, N_EDGES) - e0;
    if (t < NSUPER) hist[t] = 0;
    __syncthreads();
    for (int i = t; i < eN; i += 1024) atomicAdd(&hist[dst[e0 + i] >> 9], 1);
    __syncthreads();
    if (t == 0) {
        int run = 0;
        for (int s = 0; s < NSUPER; ++s) { pref[s] = run; run += hist[s]; }
        pref[NSUPER] = run;
    }
    __syncthreads();
    if (t < NSUPER) {
        base[t] = atomicAdd(&superCur[t], hist[t]);
        curs[t] = pref[t];
    }
    __syncthreads();
    for (int i = t; i < eN; i += 1024) {
        int d = dst[e0 + i];
        int s = d >> 9;
        int p = atomicAdd(&curs[s], 1);
        out[p] = ((unsigned)(d & 511) << 16) | (unsigned)src[e0 + i];
    }
    __syncthreads();
    for (int i = t; i < eN; i += 1024) {
        int lo = 0, hi = NSUPER;               // find super of reordered slot i
        while (lo + 1 < hi) { int mid = (lo + hi) >> 1; if (pref[mid] <= i) lo = mid; else hi = mid; }
        ebuf[base[lo] + (i - pref[lo])] = out[i];
    }
}

__global__ __launch_bounds__(512) void buildcsr_kernel(const unsigned* __restrict__ ebuf,
                                                       const int* __restrict__ superBase,
                                                       unsigned short* __restrict__ csr16,
                                                       int* __restrict__ row_ptr) {
    __shared__ int hist[SUPW];
    __shared__ int pref[SUPW];
    __shared__ int cur[SUPW];
    __shared__ unsigned short out16[CSR_CAP];
    int s = blockIdx.x, t = threadIdx.x;
    int beg = superBase[s], end = superBase[s + 1];
    int cnt = end - beg;
    hist[t] = 0;
    __syncthreads();
    for (int i = beg + t; i < end; i += 512)
        atomicAdd(&hist[(ebuf[i] >> 16) & 511], 1);
    __syncthreads();
    pref[t] = hist[t];
    __syncthreads();
    #pragma unroll
    for (int off = 1; off < 512; off <<= 1) {
        int u = (t >= off) ? pref[t - off] : 0;
        __syncthreads();
        pref[t] += u;
        __syncthreads();
    }
    int excl = pref[t] - hist[t];
    int node = s * SUPW + t;
    if (node < N_NODES) row_ptr[node] = beg + excl;
    if (s == NSUPER - 1 && t == 0) row_ptr[N_NODES] = N_EDGES;
    cur[t] = excl;
    __syncthreads();
    for (int i = beg + t; i < end; i += 512) {
        unsigned u = ebuf[i];
        int p = atomicAdd(&cur[(u >> 16) & 511], 1);
        unsigned short sv = (unsigned short)(u & 0xffff);
        if (p < CSR_CAP) out16[p] = sv;
        else csr16[beg + p] = sv;      // overflow fallback (never hit for this input)
    }
    __syncthreads();
    int lim = min(cnt, CSR_CAP);
    for (int i = t; i < lim; i += 512) csr16[beg + i] = out16[i];
}

// ---------------- fp32 -> fp16 copy (for x, layer 0) ----------------
__global__ __launch_bounds__(256) void tohalf_kernel(const float* __restrict__ in,
                                                     __half2* __restrict__ out) {
    int i = blockIdx.x * 256 + threadIdx.x;
    if (i < N_NODES * D / 2) {
        float2 v = ((const float2*)in)[i];
        out[i] = __floats2half2_rn(v.x, v.y);
    }
}

// ---------------- FUSED per-layer kernel: aggregate + 2-layer MLP -------------
// Block owns 64 node rows. Phase 1: gather-aggregate neighbors straight into
// the LDS A-transposed tile (fp32, no fp16 round-trip of z). Phase 2/3: the
// two 64x64 fp32 GEMMs in LDS (same code as previous gin_mlp).
// h double-buffered across layers: reads h2in (prev layer), writes h16out.
template <bool LAST>
__global__ __launch_bounds__(256) void gin_fused_kernel(
    const __half2* __restrict__ h2in, __half2* __restrict__ h16out,
    float* __restrict__ hout_f32,
    const int* __restrict__ row_ptr, const unsigned short* __restrict__ csr16,
    const float* __restrict__ eps, int l,
    const float* __restrict__ w1, const float* __restrict__ b1,
    const float* __restrict__ w2, const float* __restrict__ b2) {
    __shared__ float At[D][D + 1];
    __shared__ float Ws[D][D];
    __shared__ float B1s[D], B2s[D];

    int t = threadIdx.x;
    int row0 = blockIdx.x * D;

    // stage W1 + biases while gather runs
    {
        const float4* wsrc = (const float4*)w1;
        float4* wdst = (float4*)Ws;
        #pragma unroll
        for (int i = 0; i < 4; ++i) wdst[t + i * 256] = wsrc[t + i * 256];
        if (t < D) { B1s[t] = b1[t]; B2s[t] = b2[t]; }
    }

    // ---- phase 1: aggregate. 4 lanes per node; lane owns 16 features (2 uint4 chunks)
    int nl = t >> 2;              // local node [0,64)
    int q  = t & 3;               // feature quarter: chunks 2q, 2q+1
    int node = row0 + nl;
    bool nvalid = node < N_NODES;
    float epsl = 1.0f + eps[l];
    const uint4* hrows = (const uint4*)h2in;   // 8 uint4 per 128B node row

    float acc[16];
    {
        uint4 u0 = make_uint4(0, 0, 0, 0), u1 = make_uint4(0, 0, 0, 0);
        if (nvalid) {
            u0 = hrows[(size_t)node * 8 + 2 * q];
            u1 = hrows[(size_t)node * 8 + 2 * q + 1];
        }
        const __half2* hp0 = (const __half2*)&u0;
        const __half2* hp1 = (const __half2*)&u1;
        #pragma unroll
        for (int j = 0; j < 4; ++j) {
            float2 f0 = __half22float2(hp0[j]);
            float2 f1 = __half22float2(hp1[j]);
            acc[2 * j]         = epsl * f0.x;
            acc[2 * j + 1]     = epsl * f0.y;
            acc[8 + 2 * j]     = epsl * f1.x;
            acc[8 + 2 * j + 1] = epsl * f1.y;
        }
    }
    int beg = nvalid ? row_ptr[node] : 0;
    int end = nvalid ? row_ptr[node + 1] : 0;
    for (int i = beg; i < end; i += 4) {
        #pragma unroll
        for (int k = 0; k < 4; ++k) {
            bool valid = (i + k < end);
            int ii = valid ? (i + k) : beg;       // clamped safe address
            int sidx = csr16[ii];
            uint4 u0 = hrows[(size_t)sidx * 8 + 2 * q];
            uint4 u1 = hrows[(size_t)sidx * 8 + 2 * q + 1];
            const __half2* hp0 = (const __half2*)&u0;
            const __half2* hp1 = (const __half2*)&u1;
            #pragma unroll
            for (int j = 0; j < 4; ++j) {
                float2 f0 = __half22float2(hp0[j]);
                float2 f1 = __half22float2(hp1[j]);
                acc[2 * j]         += valid ? f0.x : 0.f;
                acc[2 * j + 1]     += valid ? f0.y : 0.f;
                acc[8 + 2 * j]     += valid ? f1.x : 0.f;
                acc[8 + 2 * j + 1] += valid ? f1.y : 0.f;
            }
        }
    }
    // write z (fp32) transposed into At: features q*16..q*16+15, column nl
    #pragma unroll
    for (int j = 0; j < 16; ++j) At[q * 16 + j][nl] = acc[j];
    __syncthreads();

    // ---- phase 2: GEMM1 (relu(z @ w1 + b1)) ----
    int tx = t & 15, ty = t >> 4;
    int i0 = ty * 4, j0 = tx * 4;

    float acc1[4][4];
    #pragma unroll
    for (int a = 0; a < 4; ++a)
        #pragma unroll
        for (int c = 0; c < 4; ++c) acc1[a][c] = B1s[j0 + c];
    for (int k = 0; k < D; ++k) {
        float4 av = *(const float4*)&At[k][i0];
        float4 wv = *(const float4*)&Ws[k][j0];
        acc1[0][0] += av.x * wv.x; acc1[0][1] += av.x * wv.y; acc1[0][2] += av.x * wv.z; acc1[0][3] += av.x * wv.w;
        acc1[1][0] += av.y * wv.x; acc1[1][1] += av.y * wv.y; acc1[1][2] += av.y * wv.z; acc1[1][3] += av.y * wv.w;
        acc1[2][0] += av.z * wv.x; acc1[2][1] += av.z * wv.y; acc1[2][2] += av.z * wv.z; acc1[2][3] += av.z * wv.w;
        acc1[3][0] += av.w * wv.x; acc1[3][1] += av.w * wv.y; acc1[3][2] += av.w * wv.z; acc1[3][3] += av.w * wv.w;
    }
    __syncthreads();

    #pragma unroll
    for (int a = 0; a < 4; ++a)
        #pragma unroll
        for (int c = 0; c < 4; ++c)
            At[j0 + c][i0 + a] = fmaxf(acc1[a][c], 0.f);
    {
        const float4* wsrc = (const float4*)w2;
        float4* wdst = (float4*)Ws;
        #pragma unroll
        for (int i = 0; i < 4; ++i) wdst[t + i * 256] = wsrc[t + i * 256];
    }
    __syncthreads();

    // ---- phase 3: GEMM2 (y @ w2 + b2) ----
    float acc2[4][4];
    #pragma unroll
    for (int a = 0; a < 4; ++a)
        #pragma unroll
        for (int c = 0; c < 4; ++c) acc2[a][c] = B2s[j0 + c];
    for (int k = 0; k < D; ++k) {
        float4 av = *(const float4*)&At[k][i0];
        float4 wv = *(const float4*)&Ws[k][j0];
        acc2[0][0] += av.x * wv.x; acc2[0][1] += av.x * wv.y; acc2[0][2] += av.x * wv.z; acc2[0][3] += av.x * wv.w;
        acc2[1][0] += av.y * wv.x; acc2[1][1] += av.y * wv.y; acc2[1][2] += av.y * wv.z; acc2[1][3] += av.y * wv.w;
        acc2[2][0] += av.z * wv.x; acc2[2][1] += av.z * wv.y; acc2[2][2] += av.z * wv.z; acc2[2][3] += av.z * wv.w;
        acc2[3][0] += av.w * wv.x; acc2[3][1] += av.w * wv.y; acc2[3][2] += av.w * wv.z; acc2[3][3] += av.w * wv.w;
    }

    #pragma unroll
    for (int a = 0; a < 4; ++a) {
        int row = row0 + i0 + a;
        if (row < N_NODES) {
            float4 v = make_float4(acc2[a][0], acc2[a][1], acc2[a][2], acc2[a][3]);
            if (LAST) {
                ((float4*)(hout_f32 + (size_t)row * D))[tx] = v;   // no relu on last
            } else {
                v.x = fmaxf(v.x, 0.f); v.y = fmaxf(v.y, 0.f);
                v.z = fmaxf(v.z, 0.f); v.w = fmaxf(v.w, 0.f);
                __half2* hrow = h16out + (size_t)row * 32;
                hrow[tx * 2]     = __floats2half2_rn(v.x, v.y);
                hrow[tx * 2 + 1] = __floats2half2_rn(v.z, v.w);
            }
        }
    }
}

// ---------------- head ----------------
template <bool RELU>
__global__ __launch_bounds__(256) void gemm64_kernel(const float* __restrict__ X,
                                                     const float* __restrict__ Wg,
                                                     const float* __restrict__ bg,
                                                     float* __restrict__ Y, int nrows) {
    __shared__ float At[D][D + 1];
    __shared__ float Ws[D][D];
    __shared__ float Bs[D];

    int t = threadIdx.x;
    int row0 = blockIdx.x * D;
    {
        const float4* wsrc = (const float4*)Wg;
        float4* wdst = (float4*)Ws;
        #pragma unroll
        for (int i = 0; i < 4; ++i) wdst[t + i * 256] = wsrc[t + i * 256];
        if (t < D) Bs[t] = bg[t];
    }
    #pragma unroll
    for (int ii = 0; ii < 4; ++ii) {
        int i = t + ii * 256;
        int r = i >> 4;
        int c4 = i & 15;
        int row = row0 + r;
        float4 v = (row < nrows) ? ((const float4*)(X + (size_t)row * D))[c4]
                                 : make_float4(0.f, 0.f, 0.f, 0.f);
        At[c4 * 4 + 0][r] = v.x;
        At[c4 * 4 + 1][r] = v.y;
        At[c4 * 4 + 2][r] = v.z;
        At[c4 * 4 + 3][r] = v.w;
    }
    __syncthreads();

    int tx = t & 15, ty = t >> 4;
    int i0 = ty * 4, j0 = tx * 4;
    float acc[4][4];
    #pragma unroll
    for (int a = 0; a < 4; ++a)
        #pragma unroll
        for (int c = 0; c < 4; ++c) acc[a][c] = Bs[j0 + c];
    for (int k = 0; k < D; ++k) {
        float4 av = *(const float4*)&At[k][i0];
        float4 wv = *(const float4*)&Ws[k][j0];
        acc[0][0] += av.x * wv.x; acc[0][1] += av.x * wv.y; acc[0][2] += av.x * wv.z; acc[0][3] += av.x * wv.w;
        acc[1][0] += av.y * wv.x; acc[1][1] += av.y * wv.y; acc[1][2] += av.y * wv.z; acc[1][3] += av.y * wv.w;
        acc[2][0] += av.z * wv.x; acc[2][1] += av.z * wv.y; acc[2][2] += av.z * wv.z; acc[2][3] += av.z * wv.w;
        acc[3][0] += av.w * wv.x; acc[3][1] += av.w * wv.y; acc[3][2] += av.w * wv.z; acc[3][3] += av.w * wv.w;
    }
    #pragma unroll
    for (int a = 0; a < 4; ++a) {
        int row = row0 + i0 + a;
        if (row < nrows) {
            float4 v = make_float4(acc[a][0], acc[a][1], acc[a][2], acc[a][3]);
            if (RELU) {
                v.x = fmaxf(v.x, 0.f); v.y = fmaxf(v.y, 0.f);
                v.z = fmaxf(v.z, 0.f); v.w = fmaxf(v.w, 0.f);
            }
            ((float4*)(Y + (size_t)row * D))[tx] = v;
        }
    }
}

__device__ __forceinline__ int lower_bound_i(const int* a, int n, int key) {
    int lo = 0, hi = n;
    while (lo < hi) {
        int mid = (lo + hi) >> 1;
        if (a[mid] < key) lo = mid + 1;
        else hi = mid;
    }
    return lo;
}

__global__ __launch_bounds__(256) void pool_mean_kernel(const float* __restrict__ h,
                                                        const int* __restrict__ batch,
                                                        float* __restrict__ pooled) {
    __shared__ float red[4][D];
    int g = blockIdx.x;
    int t = threadIdx.x;
    int w = t >> 6, d = t & 63;
    int start = lower_bound_i(batch, N_NODES, g);
    int end = lower_bound_i(batch, N_NODES, g + 1);
    float sum = 0.f;
    for (int i = start + w; i < end; i += 4) sum += h[(size_t)i * D + d];
    red[w][d] = sum;
    __syncthreads();
    if (w == 0) {
        int cnt = end - start;
        float tot = red[0][d] + red[1][d] + red[2][d] + red[3][d];
        pooled[g * D + d] = tot / (float)(cnt > 0 ? cnt : 1);
    }
}

__global__ __launch_bounds__(256) void head2_kernel(const float* __restrict__ tin,
                                                    const float* __restrict__ w,
                                                    const float* __restrict__ b,
                                                    float* __restrict__ out) {
    __shared__ float trow[D];
    int i = blockIdx.y;
    int j = blockIdx.x * 256 + threadIdx.x;
    if (threadIdx.x < D) trow[threadIdx.x] = tin[i * D + threadIdx.x];
    __syncthreads();
    float acc = b[j];
    #pragma unroll
    for (int k = 0; k < D; ++k) acc += trow[k] * w[k * NOUT + j];
    out[(size_t)i * NOUT + j] = acc;
}

extern "C" void kernel_launch(void* const* d_in, const int* in_sizes, int n_in,
                              void* d_out, int out_size, void* d_ws, size_t ws_size,
                              hipStream_t stream) {
    const float* x   = (const float*)d_in[0];
    const int*   ei  = (const int*)d_in[1];
    const int*   src = ei;
    const int*   dst = ei + N_EDGES;
    const int* batch = (const int*)d_in[2];
    const float* gw1 = (const float*)d_in[3];
    const float* gb1 = (const float*)d_in[4];
    const float* gw2 = (const float*)d_in[5];
    const float* gb2 = (const float*)d_in[6];
    const float* eps = (const float*)d_in[7];
    const float* wh1 = (const float*)d_in[8];
    const float* bh1 = (const float*)d_in[9];
    const float* wh2 = (const float*)d_in[10];
    const float* bh2 = (const float*)d_in[11];
    float* out = (float*)d_out;

    // workspace layout (16B-aligned chunks)
    char* p = (char*)d_ws;
    float* hfin   = (float*)p; p += (size_t)N_NODES * D * 4;   // fp32 final-layer h
    float* pooled = (float*)p; p += (size_t)NUM_GRAPHS * D * 4;
    float* thead  = (float*)p; p += (size_t)NUM_GRAPHS * D * 4;
    __half2* h16a = (__half2*)p; p += (size_t)N_NODES * D * 2; // layer h, ping
    __half2* h16b = (__half2*)p; p += (size_t)N_NODES * D * 2; // layer h, pong
    unsigned* ebuf = (unsigned*)p; p += (size_t)N_EDGES * 4;
    int* superCnt  = (int*)p; p += 128 * 4;
    int* superBase = (int*)p; p += 128 * 4;
    int* superCur  = (int*)p; p += 128 * 4;
    int* row_ptr   = (int*)p; p += 50052 * 4;
    unsigned short* csr16 = (unsigned short*)p; p += (size_t)N_EDGES * 2;

    const int nodeBlocks = (N_NODES + D - 1) / D;  // 782

    // CSR build v3 (coalesced-write counting sort)
    zero_super_kernel<<<1, 128, 0, stream>>>(superCnt);
    hist_super_kernel<<<PART_BLOCKS, 256, 0, stream>>>(dst, superCnt);
    scan_super_kernel<<<1, 128, 0, stream>>>(superCnt, superBase, superCur);
    partition_kernel<<<PART_BLOCKS, 1024, 0, stream>>>(src, dst, superCur, ebuf);
    buildcsr_kernel<<<NSUPER, 512, 0, stream>>>(ebuf, superBase, csr16, row_ptr);

    // fp16 shadow of x (layer-0 input)
    tohalf_kernel<<<(N_NODES * D / 2 + 255) / 256, 256, 0, stream>>>(x, h16a);

    // GIN layers: fused aggregate+MLP, h double-buffered (fp32 hfin on last)
    const __half2* hin = h16a;
    __half2* hout = h16b;
    for (int l = 0; l < NLAYER; ++l) {
        if (l < NLAYER - 1)
            gin_fused_kernel<false><<<nodeBlocks, 256, 0, stream>>>(
                hin, hout, hfin, row_ptr, csr16, eps, l,
                gw1 + (size_t)l * D * D, gb1 + (size_t)l * D,
                gw2 + (size_t)l * D * D, gb2 + (size_t)l * D);
        else
            gin_fused_kernel<true><<<nodeBlocks, 256, 0, stream>>>(
                hin, hout, hfin, row_ptr, csr16, eps, l,
                gw1 + (size_t)l * D * D, gb1 + (size_t)l * D,
                gw2 + (size_t)l * D * D, gb2 + (size_t)l * D);
        const __half2* tmp = hin;
        hin = hout;
        hout = (__half2*)tmp;
    }

    // pool + head
    pool_mean_kernel<<<NUM_GRAPHS, 256, 0, stream>>>(hfin, batch, pooled);
    gemm64_kernel<true><<<(NUM_GRAPHS + D - 1) / D, 256, 0, stream>>>(pooled, wh1, bh1, thead, NUM_GRAPHS);
    head2_kernel<<<dim3(NOUT / 256, NUM_GRAPHS), 256, 0, stream>>>(thead, wh2, bh2, out);
}

// Round 2
// 173.877 us; speedup vs baseline: 1.4330x; 1.2301x over previous
//
#include <hip/hip_runtime.h>
#include <hip/hip_fp16.h>

#define N_NODES 50000
#define N_EDGES 800000
#define D 64
#define NLAYER 5
#define NUM_GRAPHS 512
#define NOUT 768
#define ZSCALE 0.0625f           // z stored as fp16(z/16): exact pow2, no overflow
#define ZINV 16.0f

#define SUPW 512                 // dst nodes per super-bucket
#define NSUPER 98                // ceil(50000/512)
#define PART_EDGES 4096          // edges per partition block
#define PART_BLOCKS 196          // ceil(800000/4096)
#define CSR_CAP 16384            // LDS staging cap per super (avg ~8163)

typedef _Float16 f16x8 __attribute__((ext_vector_type(8)));
typedef float f32x4 __attribute__((ext_vector_type(4)));

// ---------------- CSR build v3: LDS-staged two-level counting sort ----------------

__global__ __launch_bounds__(128) void zero_super_kernel(int* __restrict__ superCnt) {
    int i = threadIdx.x;
    if (i < NSUPER) superCnt[i] = 0;
}

__global__ __launch_bounds__(256) void hist_super_kernel(const int* __restrict__ dst,
                                                         int* __restrict__ superCnt) {
    __shared__ int h[NSUPER];
    int t = threadIdx.x;
    if (t < NSUPER) h[t] = 0;
    __syncthreads();
    int e0 = blockIdx.x * PART_EDGES;
    int eN = min(e0 + PART_EDGES, N_EDGES) - e0;
    for (int i = t; i < eN; i += 256) atomicAdd(&h[dst[e0 + i] >> 9], 1);
    __syncthreads();
    if (t < NSUPER) atomicAdd(&superCnt[t], h[t]);
}

__global__ __launch_bounds__(128) void scan_super_kernel(const int* __restrict__ superCnt,
                                                         int* __restrict__ superBase,
                                                         int* __restrict__ superCur) {
    if (threadIdx.x == 0) {
        int run = 0;
        for (int s = 0; s < NSUPER; ++s) {
            superBase[s] = run; superCur[s] = run; run += superCnt[s];
        }
        superBase[NSUPER] = run;  // == N_EDGES
    }
}

__global__ __launch_bounds__(1024) void partition_kernel(
    const int* __restrict__ src, const int* __restrict__ dst,
    int* __restrict__ superCur, unsigned* __restrict__ ebuf) {
    __shared__ int hist[NSUPER];
    __shared__ int pref[NSUPER + 1];
    __shared__ int base[NSUPER];
    __shared__ int curs[NSUPER];
    __shared__ unsigned out[PART_EDGES];
    int t = threadIdx.x;
    int e0 = blockIdx.x * PART_EDGES;
    int eN = min(e0 + PART_EDGES, N_EDGES) - e0;
    if (t < NSUPER) hist[t] = 0;
    __syncthreads();
    for (int i = t; i < eN; i += 1024) atomicAdd(&hist[dst[e0 + i] >> 9], 1);
    __syncthreads();
    if (t == 0) {
        int run = 0;
        for (int s = 0; s < NSUPER; ++s) { pref[s] = run; run += hist[s]; }
        pref[NSUPER] = run;
    }
    __syncthreads();
    if (t < NSUPER) {
        base[t] = atomicAdd(&superCur[t], hist[t]);
        curs[t] = pref[t];
    }
    __syncthreads();
    for (int i = t; i < eN; i += 1024) {
        int d = dst[e0 + i];
        int s = d >> 9;
        int p = atomicAdd(&curs[s], 1);
        out[p] = ((unsigned)(d & 511) << 16) | (unsigned)src[e0 + i];
    }
    __syncthreads();
    for (int i = t; i < eN; i += 1024) {
        int lo = 0, hi = NSUPER;               // find super of reordered slot i
        while (lo + 1 < hi) { int mid = (lo + hi) >> 1; if (pref[mid] <= i) lo = mid; else hi = mid; }
        ebuf[base[lo] + (i - pref[lo])] = out[i];
    }
}

__global__ __launch_bounds__(512) void buildcsr_kernel(const unsigned* __restrict__ ebuf,
                                                       const int* __restrict__ superBase,
                                                       unsigned short* __restrict__ csr16,
                                                       int* __restrict__ row_ptr) {
    __shared__ int hist[SUPW];
    __shared__ int pref[SUPW];
    __shared__ int cur[SUPW];
    __shared__ unsigned short out16[CSR_CAP];
    int s = blockIdx.x, t = threadIdx.x;
    int beg = superBase[s], end = superBase[s + 1];
    int cnt = end - beg;
    hist[t] = 0;
    __syncthreads();
    for (int i = beg + t; i < end; i += 512)
        atomicAdd(&hist[(ebuf[i] >> 16) & 511], 1);
    __syncthreads();
    pref[t] = hist[t];
    __syncthreads();
    #pragma unroll
    for (int off = 1; off < 512; off <<= 1) {
        int u = (t >= off) ? pref[t - off] : 0;
        __syncthreads();
        pref[t] += u;
        __syncthreads();
    }
    int excl = pref[t] - hist[t];
    int node = s * SUPW + t;
    if (node < N_NODES) row_ptr[node] = beg + excl;
    if (s == NSUPER - 1 && t == 0) row_ptr[N_NODES] = N_EDGES;
    cur[t] = excl;
    __syncthreads();
    for (int i = beg + t; i < end; i += 512) {
        unsigned u = ebuf[i];
        int p = atomicAdd(&cur[(u >> 16) & 511], 1);
        unsigned short sv = (unsigned short)(u & 0xffff);
        if (p < CSR_CAP) out16[p] = sv;
        else csr16[beg + p] = sv;      // overflow fallback (never hit for this input)
    }
    __syncthreads();
    int lim = min(cnt, CSR_CAP);
    for (int i = t; i < lim; i += 512) csr16[beg + i] = out16[i];
}

// ---------------- fp32 -> fp16 copy (for x, layer 0) ----------------
__global__ __launch_bounds__(256) void tohalf_kernel(const float* __restrict__ in,
                                                     __half2* __restrict__ out) {
    int i = blockIdx.x * 256 + threadIdx.x;
    if (i < N_NODES * D / 2) {
        float2 v = ((const float2*)in)[i];
        out[i] = __floats2half2_rn(v.x, v.y);
    }
}

// ---------------- FUSED per-layer kernel: aggregate + MFMA 2-layer MLP ----------
// Phase 1: gather-aggregate (fp32 regs) -> Z LDS as fp16(z/16).
// Phase 2: GEMM1 via v_mfma_f32_16x16x32_f16 (A=Z, B=Wt1), relu, y/16 -> Z.
// Phase 3: GEMM2 (A=Y, B=Wt2) -> global (fp16 relu'd, or fp32 no-relu on LAST).
// Fragment layouts (16x16x32): A lane l: row=l&15, k=(l>>4)*8+j  (8 contiguous k)
//                              B lane l: col=l&15, k=(l>>4)*8+j
//                              C lane l: col=l&15, row=(l>>4)*4+reg
template <bool LAST>
__global__ __launch_bounds__(256, 3) void gin_fused_kernel(
    const __half2* __restrict__ h2in, __half2* __restrict__ h16out,
    float* __restrict__ hout_f32,
    const int* __restrict__ row_ptr, const unsigned short* __restrict__ csr16,
    const float* __restrict__ eps, int l,
    const float* __restrict__ w1, const float* __restrict__ b1,
    const float* __restrict__ w2, const float* __restrict__ b2) {
    __shared__ __align__(16) __half Z[D][72];    // 72-half row stride: 16B-aligned rows
    __shared__ __align__(16) __half Wt[D][72];   // Wt[n][k] = W[k][n] fp16
    __shared__ float B1s[D], B2s[D];

    int t = threadIdx.x;
    int row0 = blockIdx.x * D;

    // ---- stage Wt1 (transposed fp16) + biases ----
    {
        const float4* ws = (const float4*)w1;
        #pragma unroll
        for (int i = 0; i < 4; ++i) {
            int g = t + i * 256;          // float4 id: k=g>>4, cols (g&15)*4..+3
            float4 v = ws[g];
            int k = g >> 4, n0 = (g & 15) << 2;
            Wt[n0 + 0][k] = __float2half_rn(v.x);
            Wt[n0 + 1][k] = __float2half_rn(v.y);
            Wt[n0 + 2][k] = __float2half_rn(v.z);
            Wt[n0 + 3][k] = __float2half_rn(v.w);
        }
        if (t < D) { B1s[t] = b1[t]; B2s[t] = b2[t]; }
    }

    // ---- phase 1: aggregate. 4 lanes per node; lane owns 16 features ----
    int nl = t >> 2;              // local node [0,64)
    int q  = t & 3;               // feature quarter: halves q*16 .. q*16+15
    int node = row0 + nl;
    bool nvalid = node < N_NODES;
    float epsl = 1.0f + eps[l];
    const uint4* hrows = (const uint4*)h2in;   // 8 uint4 per 128B node row

    float acc[16];
    {
        uint4 u0 = make_uint4(0, 0, 0, 0), u1 = make_uint4(0, 0, 0, 0);
        if (nvalid) {
            u0 = hrows[(size_t)node * 8 + 2 * q];
            u1 = hrows[(size_t)node * 8 + 2 * q + 1];
        }
        const __half2* hp0 = (const __half2*)&u0;
        const __half2* hp1 = (const __half2*)&u1;
        #pragma unroll
        for (int j = 0; j < 4; ++j) {
            float2 f0 = __half22float2(hp0[j]);
            float2 f1 = __half22float2(hp1[j]);
            acc[2 * j]         = epsl * f0.x;
            acc[2 * j + 1]     = epsl * f0.y;
            acc[8 + 2 * j]     = epsl * f1.x;
            acc[8 + 2 * j + 1] = epsl * f1.y;
        }
    }
    int beg = nvalid ? row_ptr[node] : 0;
    int end = nvalid ? row_ptr[node + 1] : 0;
    for (int i = beg; i < end; i += 4) {
        #pragma unroll
        for (int k = 0; k < 4; ++k) {
            bool valid = (i + k < end);
            int ii = valid ? (i + k) : beg;       // clamped safe address
            int sidx = csr16[ii];
            uint4 u0 = hrows[(size_t)sidx * 8 + 2 * q];
            uint4 u1 = hrows[(size_t)sidx * 8 + 2 * q + 1];
            const __half2* hp0 = (const __half2*)&u0;
            const __half2* hp1 = (const __half2*)&u1;
            #pragma unroll
            for (int j = 0; j < 4; ++j) {
                float2 f0 = __half22float2(hp0[j]);
                float2 f1 = __half22float2(hp1[j]);
                acc[2 * j]         += valid ? f0.x : 0.f;
                acc[2 * j + 1]     += valid ? f0.y : 0.f;
                acc[8 + 2 * j]     += valid ? f1.x : 0.f;
                acc[8 + 2 * j + 1] += valid ? f1.y : 0.f;
            }
        }
    }
    // write z/16 as fp16 into Z[nl][q*16 .. q*16+15] (two 16B stores)
    {
        __half2 h0 = __floats2half2_rn(acc[0] * ZSCALE, acc[1] * ZSCALE);
        __half2 h1 = __floats2half2_rn(acc[2] * ZSCALE, acc[3] * ZSCALE);
        __half2 h2 = __floats2half2_rn(acc[4] * ZSCALE, acc[5] * ZSCALE);
        __half2 h3 = __floats2half2_rn(acc[6] * ZSCALE, acc[7] * ZSCALE);
        __half2 h4 = __floats2half2_rn(acc[8] * ZSCALE, acc[9] * ZSCALE);
        __half2 h5 = __floats2half2_rn(acc[10] * ZSCALE, acc[11] * ZSCALE);
        __half2 h6 = __floats2half2_rn(acc[12] * ZSCALE, acc[13] * ZSCALE);
        __half2 h7 = __floats2half2_rn(acc[14] * ZSCALE, acc[15] * ZSCALE);
        uint4 u0, u1;
        u0.x = *(unsigned*)&h0; u0.y = *(unsigned*)&h1; u0.z = *(unsigned*)&h2; u0.w = *(unsigned*)&h3;
        u1.x = *(unsigned*)&h4; u1.y = *(unsigned*)&h5; u1.z = *(unsigned*)&h6; u1.w = *(unsigned*)&h7;
        *(uint4*)&Z[nl][q * 16]     = u0;
        *(uint4*)&Z[nl][q * 16 + 8] = u1;
    }
    __syncthreads();

    // ---- phase 2: GEMM1 via MFMA ----
    int m  = t & 15;
    int hi = (t >> 4) & 3;
    int w  = t >> 6;

    // prefetch w2 (consumed after barrier2) — hides global latency under GEMM1
    float4 w2r[4];
    {
        const float4* ws = (const float4*)w2;
        #pragma unroll
        for (int i = 0; i < 4; ++i) w2r[i] = ws[t + i * 256];
    }

    f16x8 a0 = *(const f16x8*)&Z[w * 16 + m][hi * 8];
    f16x8 a1 = *(const f16x8*)&Z[w * 16 + m][32 + hi * 8];
    f32x4 c1[4];
    #pragma unroll
    for (int n = 0; n < 4; ++n) {
        f16x8 bf0 = *(const f16x8*)&Wt[n * 16 + m][hi * 8];
        f16x8 bf1 = *(const f16x8*)&Wt[n * 16 + m][32 + hi * 8];
        f32x4 c = {0.f, 0.f, 0.f, 0.f};
        c = __builtin_amdgcn_mfma_f32_16x16x32_f16(a0, bf0, c, 0, 0, 0);
        c = __builtin_amdgcn_mfma_f32_16x16x32_f16(a1, bf1, c, 0, 0, 0);
        c1[n] = c;
    }
    __syncthreads();   // everyone done reading Z / Wt

    // y = relu(z@w1 + b1); store y/16 fp16 back into Z. Stage Wt2.
    #pragma unroll
    for (int n = 0; n < 4; ++n) {
        int col = n * 16 + m;
        #pragma unroll
        for (int r = 0; r < 4; ++r) {
            int row = w * 16 + hi * 4 + r;
            float v = c1[n][r] * ZINV + B1s[col];
            Z[row][col] = __float2half_rn(fmaxf(v, 0.f) * ZSCALE);
        }
    }
    {
        #pragma unroll
        for (int i = 0; i < 4; ++i) {
            int g = t + i * 256;
            float4 v = w2r[i];
            int k = g >> 4, n0 = (g & 15) << 2;
            Wt[n0 + 0][k] = __float2half_rn(v.x);
            Wt[n0 + 1][k] = __float2half_rn(v.y);
            Wt[n0 + 2][k] = __float2half_rn(v.z);
            Wt[n0 + 3][k] = __float2half_rn(v.w);
        }
    }
    __syncthreads();

    // ---- phase 3: GEMM2 via MFMA + epilogue ----
    f16x8 y0 = *(const f16x8*)&Z[w * 16 + m][hi * 8];
    f16x8 y1 = *(const f16x8*)&Z[w * 16 + m][32 + hi * 8];
    f32x4 c2[4];
    #pragma unroll
    for (int n = 0; n < 4; ++n) {
        f16x8 bf0 = *(const f16x8*)&Wt[n * 16 + m][hi * 8];
        f16x8 bf1 = *(const f16x8*)&Wt[n * 16 + m][32 + hi * 8];
        f32x4 c = {0.f, 0.f, 0.f, 0.f};
        c = __builtin_amdgcn_mfma_f32_16x16x32_f16(y0, bf0, c, 0, 0, 0);
        c = __builtin_amdgcn_mfma_f32_16x16x32_f16(y1, bf1, c, 0, 0, 0);
        c2[n] = c;
    }
    #pragma unroll
    for (int n = 0; n < 4; ++n) {
        int col = n * 16 + m;
        #pragma unroll
        for (int r = 0; r < 4; ++r) {
            int grow = row0 + w * 16 + hi * 4 + r;
            if (grow < N_NODES) {
                float o = c2[n][r] * ZINV + B2s[col];
                if (LAST) {
                    hout_f32[(size_t)grow * D + col] = o;          // no relu on last
                } else {
                    ((__half*)h16out)[(size_t)grow * D + col] = __float2half_rn(fmaxf(o, 0.f));
                }
            }
        }
    }
}

// ---------------- head ----------------
template <bool RELU>
__global__ __launch_bounds__(256) void gemm64_kernel(const float* __restrict__ X,
                                                     const float* __restrict__ Wg,
                                                     const float* __restrict__ bg,
                                                     float* __restrict__ Y, int nrows) {
    __shared__ float At[D][D + 1];
    __shared__ float Ws[D][D];
    __shared__ float Bs[D];

    int t = threadIdx.x;
    int row0 = blockIdx.x * D;
    {
        const float4* wsrc = (const float4*)Wg;
        float4* wdst = (float4*)Ws;
        #pragma unroll
        for (int i = 0; i < 4; ++i) wdst[t + i * 256] = wsrc[t + i * 256];
        if (t < D) Bs[t] = bg[t];
    }
    #pragma unroll
    for (int ii = 0; ii < 4; ++ii) {
        int i = t + ii * 256;
        int r = i >> 4;
        int c4 = i & 15;
        int row = row0 + r;
        float4 v = (row < nrows) ? ((const float4*)(X + (size_t)row * D))[c4]
                                 : make_float4(0.f, 0.f, 0.f, 0.f);
        At[c4 * 4 + 0][r] = v.x;
        At[c4 * 4 + 1][r] = v.y;
        At[c4 * 4 + 2][r] = v.z;
        At[c4 * 4 + 3][r] = v.w;
    }
    __syncthreads();

    int tx = t & 15, ty = t >> 4;
    int i0 = ty * 4, j0 = tx * 4;
    float acc[4][4];
    #pragma unroll
    for (int a = 0; a < 4; ++a)
        #pragma unroll
        for (int c = 0; c < 4; ++c) acc[a][c] = Bs[j0 + c];
    for (int k = 0; k < D; ++k) {
        float4 av = *(const float4*)&At[k][i0];
        float4 wv = *(const float4*)&Ws[k][j0];
        acc[0][0] += av.x * wv.x; acc[0][1] += av.x * wv.y; acc[0][2] += av.x * wv.z; acc[0][3] += av.x * wv.w;
        acc[1][0] += av.y * wv.x; acc[1][1] += av.y * wv.y; acc[1][2] += av.y * wv.z; acc[1][3] += av.y * wv.w;
        acc[2][0] += av.z * wv.x; acc[2][1] += av.z * wv.y; acc[2][2] += av.z * wv.z; acc[2][3] += av.z * wv.w;
        acc[3][0] += av.w * wv.x; acc[3][1] += av.w * wv.y; acc[3][2] += av.w * wv.z; acc[3][3] += av.w * wv.w;
    }
    #pragma unroll
    for (int a = 0; a < 4; ++a) {
        int row = row0 + i0 + a;
        if (row < nrows) {
            float4 v = make_float4(acc[a][0], acc[a][1], acc[a][2], acc[a][3]);
            if (RELU) {
                v.x = fmaxf(v.x, 0.f); v.y = fmaxf(v.y, 0.f);
                v.z = fmaxf(v.z, 0.f); v.w = fmaxf(v.w, 0.f);
            }
            ((float4*)(Y + (size_t)row * D))[tx] = v;
        }
    }
}

__device__ __forceinline__ int lower_bound_i(const int* a, int n, int key) {
    int lo = 0, hi = n;
    while (lo < hi) {
        int mid = (lo + hi) >> 1;
        if (a[mid] < key) lo = mid + 1;
        else hi = mid;
    }
    return lo;
}

__global__ __launch_bounds__(256) void pool_mean_kernel(const float* __restrict__ h,
                                                        const int* __restrict__ batch,
                                                        float* __restrict__ pooled) {
    __shared__ float red[4][D];
    int g = blockIdx.x;
    int t = threadIdx.x;
    int w = t >> 6, d = t & 63;
    int start = lower_bound_i(batch, N_NODES, g);
    int end = lower_bound_i(batch, N_NODES, g + 1);
    float sum = 0.f;
    for (int i = start + w; i < end; i += 4) sum += h[(size_t)i * D + d];
    red[w][d] = sum;
    __syncthreads();
    if (w == 0) {
        int cnt = end - start;
        float tot = red[0][d] + red[1][d] + red[2][d] + red[3][d];
        pooled[g * D + d] = tot / (float)(cnt > 0 ? cnt : 1);
    }
}

__global__ __launch_bounds__(256) void head2_kernel(const float* __restrict__ tin,
                                                    const float* __restrict__ w,
                                                    const float* __restrict__ b,
                                                    float* __restrict__ out) {
    __shared__ float trow[D];
    int i = blockIdx.y;
    int j = blockIdx.x * 256 + threadIdx.x;
    if (threadIdx.x < D) trow[threadIdx.x] = tin[i * D + threadIdx.x];
    __syncthreads();
    float acc = b[j];
    #pragma unroll
    for (int k = 0; k < D; ++k) acc += trow[k] * w[k * NOUT + j];
    out[(size_t)i * NOUT + j] = acc;
}

extern "C" void kernel_launch(void* const* d_in, const int* in_sizes, int n_in,
                              void* d_out, int out_size, void* d_ws, size_t ws_size,
                              hipStream_t stream) {
    const float* x   = (const float*)d_in[0];
    const int*   ei  = (const int*)d_in[1];
    const int*   src = ei;
    const int*   dst = ei + N_EDGES;
    const int* batch = (const int*)d_in[2];
    const float* gw1 = (const float*)d_in[3];
    const float* gb1 = (const float*)d_in[4];
    const float* gw2 = (const float*)d_in[5];
    const float* gb2 = (const float*)d_in[6];
    const float* eps = (const float*)d_in[7];
    const float* wh1 = (const float*)d_in[8];
    const float* bh1 = (const float*)d_in[9];
    const float* wh2 = (const float*)d_in[10];
    const float* bh2 = (const float*)d_in[11];
    float* out = (float*)d_out;

    // workspace layout (16B-aligned chunks)
    char* p = (char*)d_ws;
    float* hfin   = (float*)p; p += (size_t)N_NODES * D * 4;   // fp32 final-layer h
    float* pooled = (float*)p; p += (size_t)NUM_GRAPHS * D * 4;
    float* thead  = (float*)p; p += (size_t)NUM_GRAPHS * D * 4;
    __half2* h16a = (__half2*)p; p += (size_t)N_NODES * D * 2; // layer h, ping
    __half2* h16b = (__half2*)p; p += (size_t)N_NODES * D * 2; // layer h, pong
    unsigned* ebuf = (unsigned*)p; p += (size_t)N_EDGES * 4;
    int* superCnt  = (int*)p; p += 128 * 4;
    int* superBase = (int*)p; p += 128 * 4;
    int* superCur  = (int*)p; p += 128 * 4;
    int* row_ptr   = (int*)p; p += 50052 * 4;
    unsigned short* csr16 = (unsigned short*)p; p += (size_t)N_EDGES * 2;

    const int nodeBlocks = (N_NODES + D - 1) / D;  // 782

    // CSR build v3 (coalesced-write counting sort)
    zero_super_kernel<<<1, 128, 0, stream>>>(superCnt);
    hist_super_kernel<<<PART_BLOCKS, 256, 0, stream>>>(dst, superCnt);
    scan_super_kernel<<<1, 128, 0, stream>>>(superCnt, superBase, superCur);
    partition_kernel<<<PART_BLOCKS, 1024, 0, stream>>>(src, dst, superCur, ebuf);
    buildcsr_kernel<<<NSUPER, 512, 0, stream>>>(ebuf, superBase, csr16, row_ptr);

    // fp16 shadow of x (layer-0 input)
    tohalf_kernel<<<(N_NODES * D / 2 + 255) / 256, 256, 0, stream>>>(x, h16a);

    // GIN layers: fused aggregate + MFMA MLP, h double-buffered (fp32 hfin on last)
    const __half2* hin = h16a;
    __half2* hout = h16b;
    for (int l = 0; l < NLAYER; ++l) {
        if (l < NLAYER - 1)
            gin_fused_kernel<false><<<nodeBlocks, 256, 0, stream>>>(
                hin, hout, hfin, row_ptr, csr16, eps, l,
                gw1 + (size_t)l * D * D, gb1 + (size_t)l * D,
                gw2 + (size_t)l * D * D, gb2 + (size_t)l * D);
        else
            gin_fused_kernel<true><<<nodeBlocks, 256, 0, stream>>>(
                hin, hout, hfin, row_ptr, csr16, eps, l,
                gw1 + (size_t)l * D * D, gb1 + (size_t)l * D,
                gw2 + (size_t)l * D * D, gb2 + (size_t)l * D);
        const __half2* tmp = hin;
        hin = hout;
        hout = (__half2*)tmp;
    }

    // pool + head
    pool_mean_kernel<<<NUM_GRAPHS, 256, 0, stream>>>(hfin, batch, pooled);
    gemm64_kernel<true><<<(NUM_GRAPHS + D - 1) / D, 256, 0, stream>>>(pooled, wh1, bh1, thead, NUM_GRAPHS);
    head2_kernel<<<dim3(NOUT / 256, NUM_GRAPHS), 256, 0, stream>>>(thead, wh2, bh2, out);
}

// Round 3
// 167.924 us; speedup vs baseline: 1.4838x; 1.0355x over previous
//
#include <hip/hip_runtime.h>
#include <hip/hip_fp16.h>

#define N_NODES 50000
#define N_EDGES 800000
#define D 64
#define NLAYER 5
#define NUM_GRAPHS 512
#define NOUT 768
#define ZSCALE 0.0625f           // z stored as fp16(z/16): exact pow2, no overflow
#define WSCALE 16.0f             // W staged as fp16(16*w): (z/16)@(16w) = z@w

#define SUPW 512                 // dst nodes per super-bucket
#define NSUPER 98                // ceil(50000/512)
#define PART_EDGES 4096          // edges per partition block
#define PART_BLOCKS 196          // ceil(800000/4096)
#define CSR_CAP 16384            // LDS staging cap per super (avg ~8163)

typedef _Float16 f16x8 __attribute__((ext_vector_type(8)));
typedef float f32x4 __attribute__((ext_vector_type(4)));

// ---------------- CSR build v3: LDS-staged two-level counting sort ----------------

__global__ __launch_bounds__(128) void zero_super_kernel(int* __restrict__ superCnt) {
    int i = threadIdx.x;
    if (i < NSUPER) superCnt[i] = 0;
}

__global__ __launch_bounds__(256) void hist_super_kernel(const int* __restrict__ dst,
                                                         int* __restrict__ superCnt) {
    __shared__ int h[NSUPER];
    int t = threadIdx.x;
    if (t < NSUPER) h[t] = 0;
    __syncthreads();
    int e0 = blockIdx.x * PART_EDGES;
    int eN = min(e0 + PART_EDGES, N_EDGES) - e0;
    for (int i = t; i < eN; i += 256) atomicAdd(&h[dst[e0 + i] >> 9], 1);
    __syncthreads();
    if (t < NSUPER) atomicAdd(&superCnt[t], h[t]);
}

__global__ __launch_bounds__(128) void scan_super_kernel(const int* __restrict__ superCnt,
                                                         int* __restrict__ superBase,
                                                         int* __restrict__ superCur) {
    if (threadIdx.x == 0) {
        int run = 0;
        for (int s = 0; s < NSUPER; ++s) {
            superBase[s] = run; superCur[s] = run; run += superCnt[s];
        }
        superBase[NSUPER] = run;  // == N_EDGES
    }
}

__global__ __launch_bounds__(1024) void partition_kernel(
    const int* __restrict__ src, const int* __restrict__ dst,
    int* __restrict__ superCur, unsigned* __restrict__ ebuf) {
    __shared__ int hist[NSUPER];
    __shared__ int pref[NSUPER + 1];
    __shared__ int base[NSUPER];
    __shared__ int curs[NSUPER];
    __shared__ unsigned out[PART_EDGES];
    int t = threadIdx.x;
    int e0 = blockIdx.x * PART_EDGES;
    int eN = min(e0 + PART_EDGES, N_EDGES) - e0;
    if (t < NSUPER) hist[t] = 0;
    __syncthreads();
    for (int i = t; i < eN; i += 1024) atomicAdd(&hist[dst[e0 + i] >> 9], 1);
    __syncthreads();
    if (t == 0) {
        int run = 0;
        for (int s = 0; s < NSUPER; ++s) { pref[s] = run; run += hist[s]; }
        pref[NSUPER] = run;
    }
    __syncthreads();
    if (t < NSUPER) {
        base[t] = atomicAdd(&superCur[t], hist[t]);
        curs[t] = pref[t];
    }
    __syncthreads();
    for (int i = t; i < eN; i += 1024) {
        int d = dst[e0 + i];
        int s = d >> 9;
        int p = atomicAdd(&curs[s], 1);
        out[p] = ((unsigned)(d & 511) << 16) | (unsigned)src[e0 + i];
    }
    __syncthreads();
    for (int i = t; i < eN; i += 1024) {
        int lo = 0, hi = NSUPER;               // find super of reordered slot i
        while (lo + 1 < hi) { int mid = (lo + hi) >> 1; if (pref[mid] <= i) lo = mid; else hi = mid; }
        ebuf[base[lo] + (i - pref[lo])] = out[i];
    }
}

__global__ __launch_bounds__(512) void buildcsr_kernel(const unsigned* __restrict__ ebuf,
                                                       const int* __restrict__ superBase,
                                                       unsigned short* __restrict__ csr16,
                                                       int* __restrict__ row_ptr) {
    __shared__ int hist[SUPW];
    __shared__ int pref[SUPW];
    __shared__ int cur[SUPW];
    __shared__ unsigned short out16[CSR_CAP];
    int s = blockIdx.x, t = threadIdx.x;
    int beg = superBase[s], end = superBase[s + 1];
    int cnt = end - beg;
    hist[t] = 0;
    __syncthreads();
    for (int i = beg + t; i < end; i += 512)
        atomicAdd(&hist[(ebuf[i] >> 16) & 511], 1);
    __syncthreads();
    pref[t] = hist[t];
    __syncthreads();
    #pragma unroll
    for (int off = 1; off < 512; off <<= 1) {
        int u = (t >= off) ? pref[t - off] : 0;
        __syncthreads();
        pref[t] += u;
        __syncthreads();
    }
    int excl = pref[t] - hist[t];
    int node = s * SUPW + t;
    if (node < N_NODES) row_ptr[node] = beg + excl;
    if (s == NSUPER - 1 && t == 0) row_ptr[N_NODES] = N_EDGES;
    cur[t] = excl;
    __syncthreads();
    for (int i = beg + t; i < end; i += 512) {
        unsigned u = ebuf[i];
        int p = atomicAdd(&cur[(u >> 16) & 511], 1);
        unsigned short sv = (unsigned short)(u & 0xffff);
        if (p < CSR_CAP) out16[p] = sv;
        else csr16[beg + p] = sv;      // overflow fallback (never hit for this input)
    }
    __syncthreads();
    int lim = min(cnt, CSR_CAP);
    for (int i = t; i < lim; i += 512) csr16[beg + i] = out16[i];
}

// ---------------- fp32 -> fp16 copy (for x, layer 0) ----------------
__global__ __launch_bounds__(256) void tohalf_kernel(const float* __restrict__ in,
                                                     __half2* __restrict__ out) {
    int i = blockIdx.x * 256 + threadIdx.x;
    if (i < N_NODES * D / 2) {
        float2 v = ((const float2*)in)[i];
        out[i] = __floats2half2_rn(v.x, v.y);
    }
}

// ---------------- FUSED per-layer kernel: aggregate + MFMA 2-layer MLP ----------
// Phase 1: gather-aggregate (fp32 regs via v_fma_mix) -> Z LDS as fp16(z/16).
// Phase 2: GEMM1 via v_mfma_f32_16x16x32_f16 (A=Z, B=Wt1*16), relu, y/16 -> Z.
// Phase 3: GEMM2 (A=Y, B=Wt2*16) -> global (fp16 relu'd, or fp32 no-relu on LAST).
template <bool LAST>
__global__ __launch_bounds__(256, 4) void gin_fused_kernel(
    const __half2* __restrict__ h2in, __half2* __restrict__ h16out,
    float* __restrict__ hout_f32,
    const int* __restrict__ row_ptr, const unsigned short* __restrict__ csr16,
    const float* __restrict__ eps, int l,
    const float* __restrict__ w1, const float* __restrict__ b1,
    const float* __restrict__ w2, const float* __restrict__ b2) {
    __shared__ __align__(16) __half Z[D][72];    // 72-half row stride: 16B-aligned rows
    __shared__ __align__(16) __half Wt[D][72];   // Wt[n][k] = 16*W[k][n] fp16
    __shared__ float B1s[D], B2s[D];

    int t = threadIdx.x;
    int row0 = blockIdx.x * D;

    // ---- start gather dependency chain FIRST (row_ptr -> csr16 -> h rows) ----
    int nl = t >> 2;              // local node [0,64)
    int q  = t & 3;               // feature quarter: halves q*16 .. q*16+15
    int node = row0 + nl;
    bool nvalid = node < N_NODES;
    int beg = nvalid ? row_ptr[node] : 0;
    int end = nvalid ? row_ptr[node + 1] : 0;

    // ---- stage Wt1 (transposed fp16, x16) + biases (overlaps row_ptr latency) ----
    {
        const float4* ws = (const float4*)w1;
        #pragma unroll
        for (int i = 0; i < 4; ++i) {
            int g = t + i * 256;          // float4 id: k=g>>4, cols (g&15)*4..+3
            float4 v = ws[g];
            int k = g >> 4, n0 = (g & 15) << 2;
            Wt[n0 + 0][k] = __float2half_rn(v.x * WSCALE);
            Wt[n0 + 1][k] = __float2half_rn(v.y * WSCALE);
            Wt[n0 + 2][k] = __float2half_rn(v.z * WSCALE);
            Wt[n0 + 3][k] = __float2half_rn(v.w * WSCALE);
        }
        if (t < D) { B1s[t] = b1[t]; B2s[t] = b2[t]; }
    }

    // ---- phase 1: aggregate. 4 lanes per node; lane owns 16 features ----
    float epsl = 1.0f + eps[l];
    const f16x8* hrows = (const f16x8*)h2in;   // 8 f16x8 per 128B node row

    float acc[16];
    {
        f16x8 u0 = {}, u1 = {};
        if (nvalid) {
            u0 = hrows[(size_t)node * 8 + 2 * q];
            u1 = hrows[(size_t)node * 8 + 2 * q + 1];
        }
        #pragma unroll
        for (int j = 0; j < 8; ++j) {
            acc[j]     = (float)u0[j] * epsl;
            acc[8 + j] = (float)u1[j] * epsl;
        }
    }
    for (int i = beg; i < end; i += 4) {
        #pragma unroll
        for (int k = 0; k < 4; ++k) {
            bool valid = (i + k < end);
            int ii = valid ? (i + k) : beg;       // clamped safe address
            float mult = valid ? 1.0f : 0.0f;     // one select per edge
            int sidx = csr16[ii];
            f16x8 u0 = hrows[(size_t)sidx * 8 + 2 * q];
            f16x8 u1 = hrows[(size_t)sidx * 8 + 2 * q + 1];
            #pragma unroll
            for (int j = 0; j < 8; ++j) {         // v_fma_mix_f32: f16 op_sel, f32 acc
                acc[j]     = fmaf((float)u0[j], mult, acc[j]);
                acc[8 + j] = fmaf((float)u1[j], mult, acc[8 + j]);
            }
        }
    }
    // write z/16 as fp16 into Z[nl][q*16 .. q*16+15] (two 16B stores)
    {
        f16x8 z0, z1;
        #pragma unroll
        for (int j = 0; j < 8; ++j) {
            z0[j] = (_Float16)(acc[j] * ZSCALE);
            z1[j] = (_Float16)(acc[8 + j] * ZSCALE);
        }
        *(f16x8*)&Z[nl][q * 16]     = z0;
        *(f16x8*)&Z[nl][q * 16 + 8] = z1;
    }
    __syncthreads();

    // ---- phase 2: GEMM1 via MFMA ----
    int m  = t & 15;
    int hi = (t >> 4) & 3;
    int w  = t >> 6;

    // prefetch w2 (consumed after barrier2) — hides global latency under GEMM1
    float4 w2r[4];
    {
        const float4* ws = (const float4*)w2;
        #pragma unroll
        for (int i = 0; i < 4; ++i) w2r[i] = ws[t + i * 256];
    }

    f16x8 a0 = *(const f16x8*)&Z[w * 16 + m][hi * 8];
    f16x8 a1 = *(const f16x8*)&Z[w * 16 + m][32 + hi * 8];
    f32x4 c1[4];
    #pragma unroll
    for (int n = 0; n < 4; ++n) {
        f16x8 bf0 = *(const f16x8*)&Wt[n * 16 + m][hi * 8];
        f16x8 bf1 = *(const f16x8*)&Wt[n * 16 + m][32 + hi * 8];
        f32x4 c = {0.f, 0.f, 0.f, 0.f};
        c = __builtin_amdgcn_mfma_f32_16x16x32_f16(a0, bf0, c, 0, 0, 0);
        c = __builtin_amdgcn_mfma_f32_16x16x32_f16(a1, bf1, c, 0, 0, 0);
        c1[n] = c;
    }
    __syncthreads();   // everyone done reading Z / Wt

    // y = relu(z@w1 + b1); store y/16 fp16 back into Z. Stage Wt2 (x16).
    #pragma unroll
    for (int n = 0; n < 4; ++n) {
        int col = n * 16 + m;
        #pragma unroll
        for (int r = 0; r < 4; ++r) {
            int row = w * 16 + hi * 4 + r;
            float v = c1[n][r] + B1s[col];          // Wt1 prescaled: c1 == z@w1
            Z[row][col] = __float2half_rn(fmaxf(v, 0.f) * ZSCALE);
        }
    }
    {
        #pragma unroll
        for (int i = 0; i < 4; ++i) {
            int g = t + i * 256;
            float4 v = w2r[i];
            int k = g >> 4, n0 = (g & 15) << 2;
            Wt[n0 + 0][k] = __float2half_rn(v.x * WSCALE);
            Wt[n0 + 1][k] = __float2half_rn(v.y * WSCALE);
            Wt[n0 + 2][k] = __float2half_rn(v.z * WSCALE);
            Wt[n0 + 3][k] = __float2half_rn(v.w * WSCALE);
        }
    }
    __syncthreads();

    // ---- phase 3: GEMM2 via MFMA + epilogue ----
    f16x8 y0 = *(const f16x8*)&Z[w * 16 + m][hi * 8];
    f16x8 y1 = *(const f16x8*)&Z[w * 16 + m][32 + hi * 8];
    f32x4 c2[4];
    #pragma unroll
    for (int n = 0; n < 4; ++n) {
        f16x8 bf0 = *(const f16x8*)&Wt[n * 16 + m][hi * 8];
        f16x8 bf1 = *(const f16x8*)&Wt[n * 16 + m][32 + hi * 8];
        f32x4 c = {0.f, 0.f, 0.f, 0.f};
        c = __builtin_amdgcn_mfma_f32_16x16x32_f16(y0, bf0, c, 0, 0, 0);
        c = __builtin_amdgcn_mfma_f32_16x16x32_f16(y1, bf1, c, 0, 0, 0);
        c2[n] = c;
    }
    #pragma unroll
    for (int n = 0; n < 4; ++n) {
        int col = n * 16 + m;
        #pragma unroll
        for (int r = 0; r < 4; ++r) {
            int grow = row0 + w * 16 + hi * 4 + r;
            if (grow < N_NODES) {
                float o = c2[n][r] + B2s[col];      // Wt2 prescaled: c2 == y@w2
                if (LAST) {
                    hout_f32[(size_t)grow * D + col] = o;          // no relu on last
                } else {
                    ((__half*)h16out)[(size_t)grow * D + col] = __float2half_rn(fmaxf(o, 0.f));
                }
            }
        }
    }
}

// ---------------- head ----------------
template <bool RELU>
__global__ __launch_bounds__(256) void gemm64_kernel(const float* __restrict__ X,
                                                     const float* __restrict__ Wg,
                                                     const float* __restrict__ bg,
                                                     float* __restrict__ Y, int nrows) {
    __shared__ float At[D][D + 1];
    __shared__ float Ws[D][D];
    __shared__ float Bs[D];

    int t = threadIdx.x;
    int row0 = blockIdx.x * D;
    {
        const float4* wsrc = (const float4*)Wg;
        float4* wdst = (float4*)Ws;
        #pragma unroll
        for (int i = 0; i < 4; ++i) wdst[t + i * 256] = wsrc[t + i * 256];
        if (t < D) Bs[t] = bg[t];
    }
    #pragma unroll
    for (int ii = 0; ii < 4; ++ii) {
        int i = t + ii * 256;
        int r = i >> 4;
        int c4 = i & 15;
        int row = row0 + r;
        float4 v = (row < nrows) ? ((const float4*)(X + (size_t)row * D))[c4]
                                 : make_float4(0.f, 0.f, 0.f, 0.f);
        At[c4 * 4 + 0][r] = v.x;
        At[c4 * 4 + 1][r] = v.y;
        At[c4 * 4 + 2][r] = v.z;
        At[c4 * 4 + 3][r] = v.w;
    }
    __syncthreads();

    int tx = t & 15, ty = t >> 4;
    int i0 = ty * 4, j0 = tx * 4;
    float acc[4][4];
    #pragma unroll
    for (int a = 0; a < 4; ++a)
        #pragma unroll
        for (int c = 0; c < 4; ++c) acc[a][c] = Bs[j0 + c];
    for (int k = 0; k < D; ++k) {
        float4 av = *(const float4*)&At[k][i0];
        float4 wv = *(const float4*)&Ws[k][j0];
        acc[0][0] += av.x * wv.x; acc[0][1] += av.x * wv.y; acc[0][2] += av.x * wv.z; acc[0][3] += av.x * wv.w;
        acc[1][0] += av.y * wv.x; acc[1][1] += av.y * wv.y; acc[1][2] += av.y * wv.z; acc[1][3] += av.y * wv.w;
        acc[2][0] += av.z * wv.x; acc[2][1] += av.z * wv.y; acc[2][2] += av.z * wv.z; acc[2][3] += av.z * wv.w;
        acc[3][0] += av.w * wv.x; acc[3][1] += av.w * wv.y; acc[3][2] += av.w * wv.z; acc[3][3] += av.w * wv.w;
    }
    #pragma unroll
    for (int a = 0; a < 4; ++a) {
        int row = row0 + i0 + a;
        if (row < nrows) {
            float4 v = make_float4(acc[a][0], acc[a][1], acc[a][2], acc[a][3]);
            if (RELU) {
                v.x = fmaxf(v.x, 0.f); v.y = fmaxf(v.y, 0.f);
                v.z = fmaxf(v.z, 0.f); v.w = fmaxf(v.w, 0.f);
            }
            ((float4*)(Y + (size_t)row * D))[tx] = v;
        }
    }
}

__device__ __forceinline__ int lower_bound_i(const int* a, int n, int key) {
    int lo = 0, hi = n;
    while (lo < hi) {
        int mid = (lo + hi) >> 1;
        if (a[mid] < key) lo = mid + 1;
        else hi = mid;
    }
    return lo;
}

__global__ __launch_bounds__(256) void pool_mean_kernel(const float* __restrict__ h,
                                                        const int* __restrict__ batch,
                                                        float* __restrict__ pooled) {
    __shared__ float red[4][D];
    int g = blockIdx.x;
    int t = threadIdx.x;
    int w = t >> 6, d = t & 63;
    int start = lower_bound_i(batch, N_NODES, g);
    int end = lower_bound_i(batch, N_NODES, g + 1);
    float sum = 0.f;
    for (int i = start + w; i < end; i += 4) sum += h[(size_t)i * D + d];
    red[w][d] = sum;
    __syncthreads();
    if (w == 0) {
        int cnt = end - start;
        float tot = red[0][d] + red[1][d] + red[2][d] + red[3][d];
        pooled[g * D + d] = tot / (float)(cnt > 0 ? cnt : 1);
    }
}

__global__ __launch_bounds__(256) void head2_kernel(const float* __restrict__ tin,
                                                    const float* __restrict__ w,
                                                    const float* __restrict__ b,
                                                    float* __restrict__ out) {
    __shared__ float trow[D];
    int i = blockIdx.y;
    int j = blockIdx.x * 256 + threadIdx.x;
    if (threadIdx.x < D) trow[threadIdx.x] = tin[i * D + threadIdx.x];
    __syncthreads();
    float acc = b[j];
    #pragma unroll
    for (int k = 0; k < D; ++k) acc += trow[k] * w[k * NOUT + j];
    out[(size_t)i * NOUT + j] = acc;
}

extern "C" void kernel_launch(void* const* d_in, const int* in_sizes, int n_in,
                              void* d_out, int out_size, void* d_ws, size_t ws_size,
                              hipStream_t stream) {
    const float* x   = (const float*)d_in[0];
    const int*   ei  = (const int*)d_in[1];
    const int*   src = ei;
    const int*   dst = ei + N_EDGES;
    const int* batch = (const int*)d_in[2];
    const float* gw1 = (const float*)d_in[3];
    const float* gb1 = (const float*)d_in[4];
    const float* gw2 = (const float*)d_in[5];
    const float* gb2 = (const float*)d_in[6];
    const float* eps = (const float*)d_in[7];
    const float* wh1 = (const float*)d_in[8];
    const float* bh1 = (const float*)d_in[9];
    const float* wh2 = (const float*)d_in[10];
    const float* bh2 = (const float*)d_in[11];
    float* out = (float*)d_out;

    // workspace layout (16B-aligned chunks)
    char* p = (char*)d_ws;
    float* hfin   = (float*)p; p += (size_t)N_NODES * D * 4;   // fp32 final-layer h
    float* pooled = (float*)p; p += (size_t)NUM_GRAPHS * D * 4;
    float* thead  = (float*)p; p += (size_t)NUM_GRAPHS * D * 4;
    __half2* h16a = (__half2*)p; p += (size_t)N_NODES * D * 2; // layer h, ping
    __half2* h16b = (__half2*)p; p += (size_t)N_NODES * D * 2; // layer h, pong
    unsigned* ebuf = (unsigned*)p; p += (size_t)N_EDGES * 4;
    int* superCnt  = (int*)p; p += 128 * 4;
    int* superBase = (int*)p; p += 128 * 4;
    int* superCur  = (int*)p; p += 128 * 4;
    int* row_ptr   = (int*)p; p += 50052 * 4;
    unsigned short* csr16 = (unsigned short*)p; p += (size_t)N_EDGES * 2;

    const int nodeBlocks = (N_NODES + D - 1) / D;  // 782

    // CSR build v3 (coalesced-write counting sort)
    zero_super_kernel<<<1, 128, 0, stream>>>(superCnt);
    hist_super_kernel<<<PART_BLOCKS, 256, 0, stream>>>(dst, superCnt);
    scan_super_kernel<<<1, 128, 0, stream>>>(superCnt, superBase, superCur);
    partition_kernel<<<PART_BLOCKS, 1024, 0, stream>>>(src, dst, superCur, ebuf);
    buildcsr_kernel<<<NSUPER, 512, 0, stream>>>(ebuf, superBase, csr16, row_ptr);

    // fp16 shadow of x (layer-0 input)
    tohalf_kernel<<<(N_NODES * D / 2 + 255) / 256, 256, 0, stream>>>(x, h16a);

    // GIN layers: fused aggregate + MFMA MLP, h double-buffered (fp32 hfin on last)
    const __half2* hin = h16a;
    __half2* hout = h16b;
    for (int l = 0; l < NLAYER; ++l) {
        if (l < NLAYER - 1)
            gin_fused_kernel<false><<<nodeBlocks, 256, 0, stream>>>(
                hin, hout, hfin, row_ptr, csr16, eps, l,
                gw1 + (size_t)l * D * D, gb1 + (size_t)l * D,
                gw2 + (size_t)l * D * D, gb2 + (size_t)l * D);
        else
            gin_fused_kernel<true><<<nodeBlocks, 256, 0, stream>>>(
                hin, hout, hfin, row_ptr, csr16, eps, l,
                gw1 + (size_t)l * D * D, gb1 + (size_t)l * D,
                gw2 + (size_t)l * D * D, gb2 + (size_t)l * D);
        const __half2* tmp = hin;
        hin = hout;
        hout = (__half2*)tmp;
    }

    // pool + head
    pool_mean_kernel<<<NUM_GRAPHS, 256, 0, stream>>>(hfin, batch, pooled);
    gemm64_kernel<true><<<(NUM_GRAPHS + D - 1) / D, 256, 0, stream>>>(pooled, wh1, bh1, thead, NUM_GRAPHS);
    head2_kernel<<<dim3(NOUT / 256, NUM_GRAPHS), 256, 0, stream>>>(thead, wh2, bh2, out);
}